// Round 4
// baseline (351.009 us; speedup 1.0000x reference)
//
#include <hip/hip_runtime.h>
#include <hip/hip_bf16.h>
#include <stdint.h>

#define T_   4
#define B_   16
#define NT_  196
#define C_   384
#define H_   12
#define M_   12544
#define NW_  1152              // 3*C_, wide stage-1 output
#define PBUF_ELEMS 4816896

typedef __attribute__((ext_vector_type(8))) short bf16x8;
typedef __attribute__((ext_vector_type(4))) float f32x4;

__device__ __forceinline__ void gload_lds16(const void* g, void* l) {
  typedef __attribute__((address_space(1))) const unsigned int GU32;
  typedef __attribute__((address_space(3))) unsigned int LU32;
  __builtin_amdgcn_global_load_lds((GU32*)g, (LU32*)l, 16, 0, 0);
}

__device__ __forceinline__ short f2bf_bits(float f) {
  __hip_bfloat16 h = __float2bfloat16(f);
  return *(short*)&h;
}

// SN from absmax slot (replicates reference _pow2_scale; deterministic everywhere)
__device__ __forceinline__ float sn_from_slot(const unsigned* slots, int i) {
  float m = __uint_as_float(slots[i]);
  if (m == 0.f) m = 1.f;
  float q = floorf(32.f / m);
  float sn = 0.f;
  if (q >= 1.f) { unsigned qi = (unsigned)q; sn = (float)(1u << (31 - __clz((int)qi))); }
  return sn;
}

// ---------------- absmax: grid (128, 5); y=0 -> x, y=1..4 -> W_s + b_s ----------------
__global__ __launch_bounds__(256) void absmax_all_kernel(
    const float* __restrict__ x,
    const float* __restrict__ W0, const float* __restrict__ W1,
    const float* __restrict__ W2, const float* __restrict__ W3,
    const float* __restrict__ b0, const float* __restrict__ b1,
    const float* __restrict__ b2, const float* __restrict__ b3,
    unsigned* __restrict__ slots) {
  int y = blockIdx.y;
  float m = 0.f;
  if (y == 0) {
    const float4* xv = (const float4*)x;
    for (int i = blockIdx.x * 256 + threadIdx.x; i < PBUF_ELEMS / 4; i += 128 * 256) {
      float4 v = xv[i];
      m = fmaxf(fmaxf(fmaxf(fabsf(v.x), fabsf(v.y)), fmaxf(fabsf(v.z), fabsf(v.w))), m);
    }
  } else {
    int s = y - 1;
    const float* W = (s == 0) ? W0 : (s == 1) ? W1 : (s == 2) ? W2 : W3;
    const float* bb = (s == 0) ? b0 : (s == 1) ? b1 : (s == 2) ? b2 : b3;
    for (int i = blockIdx.x * 256 + threadIdx.x; i < C_ * C_; i += 128 * 256)
      m = fmaxf(m, fabsf(W[i]));
    if (blockIdx.x == 0)
      for (int i = threadIdx.x; i < C_; i += 256) m = fmaxf(m, fabsf(bb[i]));
  }
#pragma unroll
  for (int o = 32; o > 0; o >>= 1) m = fmaxf(m, __shfl_down(m, o));
  __shared__ float sm[4];
  int wid = threadIdx.x >> 6, lane = threadIdx.x & 63;
  if (lane == 0) sm[wid] = m;
  __syncthreads();
  if (threadIdx.x == 0) {
    m = fmaxf(fmaxf(sm[0], sm[1]), fmaxf(sm[2], sm[3]));
    atomicMax(slots + y, __float_as_uint(m));
  }
}

// ---------------- quantize: grid (1176, 5); y=0 -> x (4 float4/thread), y>=1 -> W_s,b_s ----
__global__ __launch_bounds__(256) void quant_all_kernel(
    const float* __restrict__ x,
    const float* __restrict__ W0, const float* __restrict__ W1,
    const float* __restrict__ W2, const float* __restrict__ W3,
    const float* __restrict__ b0, const float* __restrict__ b1,
    const float* __restrict__ b2, const float* __restrict__ b3,
    const unsigned* __restrict__ slots,
    short* __restrict__ xq, short* __restrict__ wq, float* __restrict__ ccq) {
  int y = blockIdx.y;
  if (y == 0) {
    const float sn2 = sn_from_slot(slots, 0);
#pragma unroll
    for (int r = 0; r < 4; ++r) {
      size_t i = ((size_t)blockIdx.x * 1024 + r * 256 + threadIdx.x);
      float4 v = reinterpret_cast<const float4*>(x)[i];
      short4 o;
      o.x = f2bf_bits(truncf(v.x * sn2));
      o.y = f2bf_bits(truncf(v.y * sn2));
      o.z = f2bf_bits(truncf(v.z * sn2));
      o.w = f2bf_bits(truncf(v.w * sn2));
      reinterpret_cast<short4*>(xq)[i] = o;
    }
  } else {
    int s = y - 1;
    const float* W = (s == 0) ? W0 : (s == 1) ? W1 : (s == 2) ? W2 : W3;
    const float* bb = (s == 0) ? b0 : (s == 1) ? b1 : (s == 2) ? b2 : b3;
    const float sn1 = sn_from_slot(slots, 1 + s);
    int gid = blockIdx.x * 256 + threadIdx.x;
    if (gid < C_ * C_) wq[(size_t)s * C_ * C_ + gid] = f2bf_bits(truncf(W[gid] * sn1));
    if (gid < C_) ccq[s * C_ + gid] = truncf(bb[gid] * sn1);
  }
}

// ---------------- MFMA SC-GEMM -> i16 q, global i64 atomic stats, last-block BN finalize ----
// Aq: M x 384 bf16, Bq: ldc x 384 bf16 (N x K). 128x128 tile, BK=64.
__global__ __launch_bounds__(256) void mfma_gemm_kernel(
    const short* __restrict__ Aq, const short* __restrict__ Bq,
    const float* __restrict__ cc, const unsigned* __restrict__ slots,
    int sn2_slot, int sn1_base, int ldc, int nblk,
    short* __restrict__ out, unsigned long long* __restrict__ sums,
    unsigned* __restrict__ cnt, float* __restrict__ bn) {
  __shared__ short As[8192];   // 128 rows x 64 bf16, XOR-swizzled
  __shared__ short Bs[8192];
  __shared__ unsigned long long sred[128][2];
  __shared__ int lastflag;
  const int tid = threadIdx.x;
  const int lane = tid & 63;
  const int wid = tid >> 6;
  const int wm = wid >> 1, wn = wid & 1;
  const int m0 = blockIdx.x * 128;
  const int n0 = blockIdx.y * 128;
  if (tid < 128) { sred[tid][0] = 0ull; sred[tid][1] = 0ull; }
  f32x4 acc[4][4];
#pragma unroll
  for (int i = 0; i < 4; ++i)
#pragma unroll
    for (int j = 0; j < 4; ++j) acc[i][j] = (f32x4){0.f, 0.f, 0.f, 0.f};

  for (int k0 = 0; k0 < C_; k0 += 64) {
#pragma unroll
    for (int p = 0; p < 4; ++p) {
      int o = p * 4096 + tid * 16;
      int row = o >> 7;
      int slot = (o >> 4) & 7;
      int hs = slot ^ (row & 7);                 // inverse-swizzled global slot
      int ldsoff = p * 4096 + (tid & ~63) * 16;  // wave-uniform base
      gload_lds16(Aq + (size_t)(m0 + row) * C_ + k0 + hs * 8, (char*)As + ldsoff);
      gload_lds16(Bq + (size_t)(n0 + row) * C_ + k0 + hs * 8, (char*)Bs + ldsoff);
    }
    __syncthreads();
#pragma unroll
    for (int kk = 0; kk < 2; ++kk) {
      bf16x8 af[4], bfr[4];
#pragma unroll
      for (int i = 0; i < 4; ++i) {
        int r = wm * 64 + i * 16 + (lane & 15);
        int h = kk * 4 + (lane >> 4);
        af[i] = *(const bf16x8*)((const char*)As + r * 128 + ((h ^ (r & 7)) << 4));
        int c = wn * 64 + i * 16 + (lane & 15);
        bfr[i] = *(const bf16x8*)((const char*)Bs + c * 128 + ((h ^ (c & 7)) << 4));
      }
#pragma unroll
      for (int i = 0; i < 4; ++i)
#pragma unroll
        for (int j = 0; j < 4; ++j)
          acc[i][j] = __builtin_amdgcn_mfma_f32_16x16x32_bf16(af[i], bfr[j], acc[i][j], 0, 0, 0);
    }
    __syncthreads();
  }
  const float SN2 = (sn2_slot < 0) ? 32.f : sn_from_slot(slots, sn2_slot);
  const float invSN2 = 1.0f / SN2;             // exact pow2
  long long s1[4] = {0, 0, 0, 0}, s2[4] = {0, 0, 0, 0};
#pragma unroll
  for (int j = 0; j < 4; ++j) {
    int gcol = n0 + wn * 64 + j * 16 + (lane & 15);
    float ccv = cc[gcol];
#pragma unroll
    for (int i = 0; i < 4; ++i) {
#pragma unroll
      for (int r = 0; r < 4; ++r) {
        int grow = m0 + wm * 64 + i * 16 + (lane >> 4) * 4 + r;
        float qf = truncf(acc[i][j][r] * invSN2) + ccv;   // exact small integer
        long long qi = (long long)qf;
        out[(size_t)grow * ldc + gcol] = (short)qi;       // |q| << 32767 (see analysis)
        s1[j] += qi; s2[j] += qi * qi;
      }
    }
  }
#pragma unroll
  for (int j = 0; j < 4; ++j) {
    s1[j] += __shfl_xor(s1[j], 16); s1[j] += __shfl_xor(s1[j], 32);
    s2[j] += __shfl_xor(s2[j], 16); s2[j] += __shfl_xor(s2[j], 32);
  }
  if (lane < 16) {
#pragma unroll
    for (int j = 0; j < 4; ++j) {
      int cl = wn * 64 + j * 16 + lane;
      atomicAdd(&sred[cl][0], (unsigned long long)s1[j]);
      atomicAdd(&sred[cl][1], (unsigned long long)s2[j]);
    }
  }
  __syncthreads();
  if (tid < 128) {
    atomicAdd(&sums[(size_t)(n0 + tid) * 2 + 0], sred[tid][0]);
    atomicAdd(&sums[(size_t)(n0 + tid) * 2 + 1], sred[tid][1]);
  }
  // last-block BN finalization (device-scope atomics only; exact i64 -> f64 path)
  __threadfence();
  if (tid == 0) lastflag = (atomicAdd(cnt, 1u) == (unsigned)(nblk - 1)) ? 1 : 0;
  __syncthreads();
  if (lastflag) {
    for (int c = tid; c < ldc; c += 256) {
      long long S1 = (long long)atomicAdd(&sums[(size_t)c * 2 + 0], 0ull);
      long long S2 = (long long)atomicAdd(&sums[(size_t)c * 2 + 1], 0ull);
      double inv = 1.0 / (double)sn_from_slot(slots, sn1_base + c / C_);
      double s = (double)S1 * inv;          // exact
      double ss = (double)S2 * inv * inv;   // exact
      double mean = s / (double)M_;
      float m32 = (float)mean;
      double md = (double)m32;
      double var = (ss - 2.0 * md * s + (double)M_ * md * md) / (double)M_;
      bn[c * 2 + 0] = m32;
      bn[c * 2 + 1] = sqrtf((float)var + 1e-5f);
    }
  }
}

// ---------------- LIF ----------------
__device__ __forceinline__ float lif_step(float& v, float x, float vth) {
  v = v + (x - v) * 0.5f;
  float u = v - vth;
  float spike = (u >= 0.0f) ? 1.0f : 0.0f;
  v = (u >= 0.0f) ? 0.0f : v;
  return spike;
}

// BN + LIF + bit-pack; grid (NT_, B_, 3); reads i16 q
__global__ __launch_bounds__(384) void bn_lif_pack_kernel(
    const short* __restrict__ pw, const float* __restrict__ bn,
    const unsigned* __restrict__ slots,
    const float* __restrict__ g0, const float* __restrict__ g1, const float* __restrict__ g2,
    const float* __restrict__ be0, const float* __restrict__ be1, const float* __restrict__ be2,
    uint32_t* __restrict__ pack) {
  int c = threadIdx.x;
  int n = blockIdx.x, b = blockIdx.y, z = blockIdx.z;
  const float* g  = (z == 0) ? g0 : (z == 1) ? g1 : g2;
  const float* be = (z == 0) ? be0 : (z == 1) ? be1 : be2;
  int cg = z * C_ + c;
  float invSN1 = 1.0f / sn_from_slot(slots, 1 + z);
  float mean = bn[cg * 2 + 0], sd = bn[cg * 2 + 1];
  float gg = g[c], bb = be[c];
  int h = c >> 5;
  float v = 0.f;
  uint32_t* pko = pack + (size_t)z * (T_ * B_ * H_ * NT_);
  for (int t = 0; t < T_; ++t) {
    size_t row = (size_t)(t * B_ + b) * NT_ + n;
    float p = (float)pw[row * NW_ + cg] * invSN1;  // == stored f32 p (exact pow2)
    float o = (gg * (p - mean)) / sd + bb;
    float spike = lif_step(v, o, 1.0f);
    unsigned long long m = __ballot(spike != 0.0f);
    if ((c & 31) == 0) {
      uint32_t pt = (c & 32) ? (uint32_t)(m >> 32) : (uint32_t)m;
      pko[((size_t)(t * B_ + b) * H_ + h) * NT_ + n] = pt;
    }
  }
}

// ---------------- attention fused: Z = k^T v (recomputed per chunk), q·Z, attn_lif ----------
// grid (B_*H_, 4 chunks of 49 tokens); writes 32*spike bf16
__global__ __launch_bounds__(256) void attn_fused_kernel(
    const uint32_t* __restrict__ qp, const uint32_t* __restrict__ kp,
    const uint32_t* __restrict__ vp, short* __restrict__ yq) {
  __shared__ uint32_t kT[32][8], vT[32][8];
  __shared__ int Zs[32][32];
  const int bh = blockIdx.x, chunk = blockIdx.y;
  const int b = bh / H_, h = bh % H_;
  const int tid = threadIdx.x, lane = tid & 63, w = tid >> 6;
  const int d = tid & 31, nn = tid >> 5;
  const short one32 = f2bf_bits(32.f);
  const short zer = 0;
  float vst[7];
#pragma unroll
  for (int i = 0; i < 7; ++i) vst[i] = 0.f;
  for (int t = 0; t < T_; ++t) {
    int tbh = (t * B_ + b) * H_ + h;
    size_t base = (size_t)tbh * NT_;
    uint32_t km = (tid < NT_) ? kp[base + tid] : 0u;
    uint32_t vm = (tid < NT_) ? vp[base + tid] : 0u;
#pragma unroll
    for (int j = 0; j < 32; ++j) {
      unsigned long long bk = __ballot((km >> j) & 1u);
      unsigned long long bv = __ballot((vm >> j) & 1u);
      if (lane == 0) {
        kT[j][2 * w] = (uint32_t)bk; kT[j][2 * w + 1] = (uint32_t)(bk >> 32);
        vT[j][2 * w] = (uint32_t)bv; vT[j][2 * w + 1] = (uint32_t)(bv >> 32);
      }
    }
    __syncthreads();
    for (int pz = tid; pz < 1024; pz += 256) {
      int j = pz >> 5, dd = pz & 31;
      int zz = 0;
#pragma unroll
      for (int ww = 0; ww < 8; ++ww) zz += __popc(kT[j][ww] & vT[dd][ww]);
      Zs[j][dd] = zz;
    }
    __syncthreads();
    int zc[32];
#pragma unroll
    for (int j = 0; j < 32; ++j) zc[j] = Zs[j][d];
#pragma unroll
    for (int i = 0; i < 7; ++i) {
      int no = i * 8 + nn;
      if (no < 49) {
        int n = chunk * 49 + no;
        uint32_t qm = qp[base + n];
        int a = 0;
#pragma unroll
        for (int j = 0; j < 32; ++j) a += ((qm >> j) & 1u) ? zc[j] : 0;
        float y = 0.125f * (float)a;          // exact multiple of 1/8
        float v = vst[i];
        v = v + (y - v) * 0.5f;
        short outv;
        if (v - 0.5f >= 0.f) { v = 0.f; outv = one32; } else { outv = zer; }
        vst[i] = v;
        yq[((size_t)(t * B_ + b) * NT_ + n) * C_ + h * 32 + d] = outv;
      }
    }
    __syncthreads();
  }
}

// final BN + LIF -> d_out (f32 spikes); reads i16 q
__global__ __launch_bounds__(384) void bn_lif_out_kernel(
    const short* __restrict__ p2, const float* __restrict__ bn,
    const unsigned* __restrict__ slots,
    const float* __restrict__ g, const float* __restrict__ beta,
    float* __restrict__ out) {
  int c = threadIdx.x, n = blockIdx.x, b = blockIdx.y;
  float invSN1 = 1.0f / sn_from_slot(slots, 4);
  float mean = bn[c * 2 + 0], sd = bn[c * 2 + 1];
  float gg = g[c], bb = beta[c];
  float v = 0.f;
  for (int t = 0; t < T_; ++t) {
    size_t idx = ((size_t)(t * B_ + b) * NT_ + n) * C_ + c;
    float p = (float)p2[idx] * invSN1;
    float o = (gg * (p - mean)) / sd + bb;
    out[idx] = lif_step(v, o, 1.0f);
  }
}

// ---------------- launcher (8 dispatches + 1 memset) ----------------
extern "C" void kernel_launch(void* const* d_in, const int* in_sizes, int n_in,
                              void* d_out, int out_size, void* d_ws, size_t ws_size,
                              hipStream_t stream) {
  (void)in_sizes; (void)n_in; (void)out_size; (void)ws_size;
  const float* x = (const float*)d_in[0];
  const float* W[4]  = {(const float*)d_in[1],  (const float*)d_in[5],
                        (const float*)d_in[9],  (const float*)d_in[13]};
  const float* bv[4] = {(const float*)d_in[2],  (const float*)d_in[6],
                        (const float*)d_in[10], (const float*)d_in[14]};
  const float* g[4]  = {(const float*)d_in[3],  (const float*)d_in[7],
                        (const float*)d_in[11], (const float*)d_in[15]};
  const float* be[4] = {(const float*)d_in[4],  (const float*)d_in[8],
                        (const float*)d_in[12], (const float*)d_in[16]};
  float* out = (float*)d_out;

  char* ws = (char*)d_ws;
  unsigned*           slots = (unsigned*)(ws + 0x0000);   // [16] u32
  unsigned*           cnt1  = (unsigned*)(ws + 0x0040);
  unsigned*           cnt2  = (unsigned*)(ws + 0x0044);
  unsigned long long* sums1 = (unsigned long long*)(ws + 0x0080);  // [1152][2] i64
  unsigned long long* sums2 = (unsigned long long*)(ws + 0x4880);  // [384][2] i64
  float*              bn1   = (float*)(ws + 0x8000);      // [1152][2] f32
  float*              bn2   = (float*)(ws + 0xB000);      // [384][2] f32
  float*              ccq   = (float*)(ws + 0xC000);      // [4][384] f32
  uint32_t*           pack  = (uint32_t*)(ws + 0x10000);  // [3][150528] u32
  short*              wq    = (short*)(ws + 0x200000);    // [4][384][384] bf16
  short*              xq    = (short*)(ws + 0x400000);    // [12544][384] bf16
  short*              yq    = (short*)(ws + 0xE00000);    // [12544][384] bf16 (32*spike)
  short*              pwide = (short*)(ws + 0x1800000);   // [12544][1152] i16 q
  short*              p2    = (short*)(ws + 0x3400000);   // [12544][384] i16 q

  hipMemsetAsync(ws, 0, 0x6100, stream);  // slots + cnts + sums

  absmax_all_kernel<<<dim3(128, 5), 256, 0, stream>>>(
      x, W[0], W[1], W[2], W[3], bv[0], bv[1], bv[2], bv[3], slots);
  quant_all_kernel<<<dim3(1176, 5), 256, 0, stream>>>(
      x, W[0], W[1], W[2], W[3], bv[0], bv[1], bv[2], bv[3], slots, xq, wq, ccq);

  // stage 1: wide GEMM (N=1152 = q|k|v) + fused stats/BN, then BN+LIF+pack
  mfma_gemm_kernel<<<dim3(98, 9), 256, 0, stream>>>(
      xq, wq, ccq, slots, 0, 1, NW_, 98 * 9, pwide, sums1, cnt1, bn1);
  bn_lif_pack_kernel<<<dim3(NT_, B_, 3), 384, 0, stream>>>(
      pwide, bn1, slots, g[0], g[1], g[2], be[0], be[1], be[2], pack);

  // attention + attn_lif fused (Z = k^T v per (t,b,h), q·Z·0.125, vth=0.5)
  attn_fused_kernel<<<dim3(B_ * H_, 4), 256, 0, stream>>>(
      pack, pack + 150528, pack + 2 * 150528, yq);

  // stage 2: proj GEMM + fused stats/BN, then BN+LIF -> out
  mfma_gemm_kernel<<<dim3(98, 3), 256, 0, stream>>>(
      yq, wq + 3ull * C_ * C_, ccq + 3 * C_, slots, -1, 4, C_, 98 * 3, p2, sums2, cnt2, bn2);
  bn_lif_out_kernel<<<dim3(NT_, B_), 384, 0, stream>>>(p2, bn2, slots, g[3], be[3], out);
}

// Round 5
// 251.300 us; speedup vs baseline: 1.3968x; 1.3968x over previous
//
#include <hip/hip_runtime.h>
#include <hip/hip_bf16.h>
#include <stdint.h>

#define T_   4
#define B_   16
#define NT_  196
#define C_   384
#define H_   12
#define M_   12544
#define NW_  1152              // 3*C_, wide stage-1 output
#define PBUF_ELEMS 4816896

typedef __attribute__((ext_vector_type(8))) short bf16x8;
typedef __attribute__((ext_vector_type(4))) float f32x4;

__device__ __forceinline__ void gload_lds16(const void* g, void* l) {
  typedef __attribute__((address_space(1))) const unsigned int GU32;
  typedef __attribute__((address_space(3))) unsigned int LU32;
  __builtin_amdgcn_global_load_lds((GU32*)g, (LU32*)l, 16, 0, 0);
}

__device__ __forceinline__ short f2bf_bits(float f) {
  __hip_bfloat16 h = __float2bfloat16(f);
  return *(short*)&h;
}

// SN from absmax slot (replicates reference _pow2_scale)
__device__ __forceinline__ float sn_from_slot(const unsigned* slots, int i) {
  float m = __uint_as_float(slots[i]);
  if (m == 0.f) m = 1.f;
  float q = floorf(32.f / m);
  float sn = 0.f;
  if (q >= 1.f) { unsigned qi = (unsigned)q; sn = (float)(1u << (31 - __clz((int)qi))); }
  return sn;
}

// ---------------- absmax: grid (128, 5); y=0 -> x, y=1..4 -> W_s + b_s ----------------
__global__ __launch_bounds__(256) void absmax_all_kernel(
    const float* __restrict__ x,
    const float* __restrict__ W0, const float* __restrict__ W1,
    const float* __restrict__ W2, const float* __restrict__ W3,
    const float* __restrict__ b0, const float* __restrict__ b1,
    const float* __restrict__ b2, const float* __restrict__ b3,
    unsigned* __restrict__ slots) {
  int y = blockIdx.y;
  float m = 0.f;
  if (y == 0) {
    const float4* xv = (const float4*)x;
    for (int i = blockIdx.x * 256 + threadIdx.x; i < PBUF_ELEMS / 4; i += 128 * 256) {
      float4 v = xv[i];
      m = fmaxf(fmaxf(fmaxf(fabsf(v.x), fabsf(v.y)), fmaxf(fabsf(v.z), fabsf(v.w))), m);
    }
  } else {
    int s = y - 1;
    const float* W = (s == 0) ? W0 : (s == 1) ? W1 : (s == 2) ? W2 : W3;
    const float* bb = (s == 0) ? b0 : (s == 1) ? b1 : (s == 2) ? b2 : b3;
    for (int i = blockIdx.x * 256 + threadIdx.x; i < C_ * C_; i += 128 * 256)
      m = fmaxf(m, fabsf(W[i]));
    if (blockIdx.x == 0)
      for (int i = threadIdx.x; i < C_; i += 256) m = fmaxf(m, fabsf(bb[i]));
  }
#pragma unroll
  for (int o = 32; o > 0; o >>= 1) m = fmaxf(m, __shfl_down(m, o));
  __shared__ float sm[4];
  int wid = threadIdx.x >> 6, lane = threadIdx.x & 63;
  if (lane == 0) sm[wid] = m;
  __syncthreads();
  if (threadIdx.x == 0) {
    m = fmaxf(fmaxf(sm[0], sm[1]), fmaxf(sm[2], sm[3]));
    atomicMax(slots + y, __float_as_uint(m));
  }
}

// ---------------- quantize: grid (1176, 5); y=0 -> x, y>=1 -> W_s,b_s ----------------
__global__ __launch_bounds__(256) void quant_all_kernel(
    const float* __restrict__ x,
    const float* __restrict__ W0, const float* __restrict__ W1,
    const float* __restrict__ W2, const float* __restrict__ W3,
    const float* __restrict__ b0, const float* __restrict__ b1,
    const float* __restrict__ b2, const float* __restrict__ b3,
    const unsigned* __restrict__ slots,
    short* __restrict__ xq, short* __restrict__ wq, float* __restrict__ ccq) {
  int y = blockIdx.y;
  if (y == 0) {
    const float sn2 = sn_from_slot(slots, 0);
#pragma unroll
    for (int r = 0; r < 4; ++r) {
      size_t i = ((size_t)blockIdx.x * 1024 + r * 256 + threadIdx.x);
      float4 v = reinterpret_cast<const float4*>(x)[i];
      short4 o;
      o.x = f2bf_bits(truncf(v.x * sn2));
      o.y = f2bf_bits(truncf(v.y * sn2));
      o.z = f2bf_bits(truncf(v.z * sn2));
      o.w = f2bf_bits(truncf(v.w * sn2));
      reinterpret_cast<short4*>(xq)[i] = o;
    }
  } else {
    int s = y - 1;
    const float* W = (s == 0) ? W0 : (s == 1) ? W1 : (s == 2) ? W2 : W3;
    const float* bb = (s == 0) ? b0 : (s == 1) ? b1 : (s == 2) ? b2 : b3;
    const float sn1 = sn_from_slot(slots, 1 + s);
    int gid = blockIdx.x * 256 + threadIdx.x;
    if (gid < C_ * C_) wq[(size_t)s * C_ * C_ + gid] = f2bf_bits(truncf(W[gid] * sn1));
    if (gid < C_) ccq[s * C_ + gid] = truncf(bb[gid] * sn1);
  }
}

// ---------------- MFMA SC-GEMM -> i16 q (LDS-repacked coalesced stores) + per-block stats ----
// Aq: M x 384 bf16, Bq: ldc x 384 bf16 (N x K). 128x128 tile, BK=64.
// NO device-scope fences/atomics (R4 post-mortem: they forced L2 writeback, +100us).
__global__ __launch_bounds__(256) void mfma_gemm_kernel(
    const short* __restrict__ Aq, const short* __restrict__ Bq,
    const float* __restrict__ cc, const unsigned* __restrict__ slots,
    int sn2_slot, int ldc,
    short* __restrict__ out, long long* __restrict__ part) {
  __shared__ short smem[16384];   // k-loop: As=smem[0:8192), Bs=smem[8192:); epilogue: 128x128 i16 tile
  __shared__ unsigned long long sred[128][2];
  char* As = (char*)smem;
  char* Bs = (char*)(smem + 8192);
  const int tid = threadIdx.x;
  const int lane = tid & 63;
  const int wid = tid >> 6;
  const int wm = wid >> 1, wn = wid & 1;
  const int m0 = blockIdx.x * 128;
  const int n0 = blockIdx.y * 128;
  if (tid < 128) { sred[tid][0] = 0ull; sred[tid][1] = 0ull; }
  f32x4 acc[4][4];
#pragma unroll
  for (int i = 0; i < 4; ++i)
#pragma unroll
    for (int j = 0; j < 4; ++j) acc[i][j] = (f32x4){0.f, 0.f, 0.f, 0.f};

  for (int k0 = 0; k0 < C_; k0 += 64) {
#pragma unroll
    for (int p = 0; p < 4; ++p) {
      int o = p * 4096 + tid * 16;
      int row = o >> 7;                          // 128 B per row
      int slot = (o >> 4) & 7;
      int hs = slot ^ (row & 7);                 // inverse-swizzled global slot
      int ldsoff = p * 4096 + (tid & ~63) * 16;  // wave-uniform base
      gload_lds16(Aq + (size_t)(m0 + row) * C_ + k0 + hs * 8, As + ldsoff);
      gload_lds16(Bq + (size_t)(n0 + row) * C_ + k0 + hs * 8, Bs + ldsoff);
    }
    __syncthreads();
#pragma unroll
    for (int kk = 0; kk < 2; ++kk) {
      bf16x8 af[4], bfr[4];
#pragma unroll
      for (int i = 0; i < 4; ++i) {
        int r = wm * 64 + i * 16 + (lane & 15);
        int h = kk * 4 + (lane >> 4);
        af[i] = *(const bf16x8*)(As + r * 128 + ((h ^ (r & 7)) << 4));
        int c = wn * 64 + i * 16 + (lane & 15);
        bfr[i] = *(const bf16x8*)(Bs + c * 128 + ((h ^ (c & 7)) << 4));
      }
#pragma unroll
      for (int i = 0; i < 4; ++i)
#pragma unroll
        for (int j = 0; j < 4; ++j)
          acc[i][j] = __builtin_amdgcn_mfma_f32_16x16x32_bf16(af[i], bfr[j], acc[i][j], 0, 0, 0);
    }
    __syncthreads();
  }

  // ---- epilogue: q = trunc(acc/SN2) + cc (exact small int); stats; LDS-repacked i16 store ----
  const float SN2 = (sn2_slot < 0) ? 32.f : sn_from_slot(slots, sn2_slot);
  const float invSN2 = 1.0f / SN2;   // exact pow2
  long long s1[4] = {0, 0, 0, 0}, s2[4] = {0, 0, 0, 0};
#pragma unroll
  for (int j = 0; j < 4; ++j) {
    int tc = wn * 64 + j * 16 + (lane & 15);
    float ccv = cc[n0 + tc];
#pragma unroll
    for (int i = 0; i < 4; ++i) {
#pragma unroll
      for (int r = 0; r < 4; ++r) {
        int tr = wm * 64 + i * 16 + (lane >> 4) * 4 + r;
        float qf = truncf(acc[i][j][r] * invSN2) + ccv;
        long long qi = (long long)qf;
        int byte = (tr * 256 + tc * 2) ^ ((tr & 7) << 4);  // XOR-swizzle vs bank conflicts
        *(short*)((char*)smem + byte) = (short)qi;
        s1[j] += qi; s2[j] += qi * qi;
      }
    }
  }
#pragma unroll
  for (int j = 0; j < 4; ++j) {
    s1[j] += __shfl_xor(s1[j], 16); s1[j] += __shfl_xor(s1[j], 32);
    s2[j] += __shfl_xor(s2[j], 16); s2[j] += __shfl_xor(s2[j], 32);
  }
  if (lane < 16) {
#pragma unroll
    for (int j = 0; j < 4; ++j) {
      int cl = wn * 64 + j * 16 + lane;
      atomicAdd(&sred[cl][0], (unsigned long long)s1[j]);
      atomicAdd(&sred[cl][1], (unsigned long long)s2[j]);
    }
  }
  __syncthreads();
  if (tid < 128) {
    part[((size_t)blockIdx.x * ldc + n0 + tid) * 2 + 0] = (long long)sred[tid][0];
    part[((size_t)blockIdx.x * ldc + n0 + tid) * 2 + 1] = (long long)sred[tid][1];
  }
  // linear coalesced store: 16 lanes cover one full 256B row segment
  for (int i2 = tid; i2 < 2048; i2 += 256) {
    int tr = i2 >> 4, slot = i2 & 15;
    int byte = (tr * 256 + slot * 16) ^ ((tr & 7) << 4);
    ulonglong2 v = *(ulonglong2*)((char*)smem + byte);
    *(ulonglong2*)((char*)out + ((size_t)(m0 + tr) * ldc + n0) * 2 + slot * 16) = v;
  }
}

// ---------------- BN params from exact integer partials; grid (nseg), 384 thr ----------------
__global__ __launch_bounds__(384) void stats_final_kernel(
    const long long* __restrict__ part, const unsigned* __restrict__ slots, int sn1_base, int Ld,
    float* __restrict__ bn) {
  int c = blockIdx.x * 384 + threadIdx.x;
  long long S1 = 0, S2 = 0;
  for (int b = 0; b < 98; ++b) {
    S1 += part[((size_t)b * Ld + c) * 2 + 0];
    S2 += part[((size_t)b * Ld + c) * 2 + 1];
  }
  double inv = 1.0 / (double)sn_from_slot(slots, sn1_base + blockIdx.x);
  double s = (double)S1 * inv;          // exact
  double s2 = (double)S2 * inv * inv;   // exact
  double mean = s / (double)M_;
  float m32 = (float)mean;
  double md = (double)m32;
  double var = (s2 - 2.0 * md * s + (double)M_ * md * md) / (double)M_;
  bn[c * 2 + 0] = m32;
  bn[c * 2 + 1] = sqrtf((float)var + 1e-5f);
}

// ---------------- LIF ----------------
__device__ __forceinline__ float lif_step(float& v, float x, float vth) {
  v = v + (x - v) * 0.5f;
  float u = v - vth;
  float spike = (u >= 0.0f) ? 1.0f : 0.0f;
  v = (u >= 0.0f) ? 0.0f : v;
  return spike;
}

// BN + LIF + bit-pack; grid (NT_, B_, 3); reads i16 q
__global__ __launch_bounds__(384) void bn_lif_pack_kernel(
    const short* __restrict__ pw, const float* __restrict__ bn,
    const unsigned* __restrict__ slots,
    const float* __restrict__ g0, const float* __restrict__ g1, const float* __restrict__ g2,
    const float* __restrict__ be0, const float* __restrict__ be1, const float* __restrict__ be2,
    uint32_t* __restrict__ pack) {
  int c = threadIdx.x;
  int n = blockIdx.x, b = blockIdx.y, z = blockIdx.z;
  const float* g  = (z == 0) ? g0 : (z == 1) ? g1 : g2;
  const float* be = (z == 0) ? be0 : (z == 1) ? be1 : be2;
  int cg = z * C_ + c;
  float invSN1 = 1.0f / sn_from_slot(slots, 1 + z);
  float mean = bn[cg * 2 + 0], sd = bn[cg * 2 + 1];
  float gg = g[c], bb = be[c];
  int h = c >> 5;
  float v = 0.f;
  uint32_t* pko = pack + (size_t)z * (T_ * B_ * H_ * NT_);
  for (int t = 0; t < T_; ++t) {
    size_t row = (size_t)(t * B_ + b) * NT_ + n;
    float p = (float)pw[row * NW_ + cg] * invSN1;  // == f32 p exactly (pow2 scale)
    float o = (gg * (p - mean)) / sd + bb;
    float spike = lif_step(v, o, 1.0f);
    unsigned long long m = __ballot(spike != 0.0f);
    if ((c & 31) == 0) {
      uint32_t pt = (c & 32) ? (uint32_t)(m >> 32) : (uint32_t)m;
      pko[((size_t)(t * B_ + b) * H_ + h) * NT_ + n] = pt;
    }
  }
}

// ---------------- attention fused: Z = k^T v, q·Z·0.125, attn_lif; writes 32*spike bf16 -------
// grid (B_*H_, 4 chunks of 49 tokens)
__global__ __launch_bounds__(256) void attn_fused_kernel(
    const uint32_t* __restrict__ qp, const uint32_t* __restrict__ kp,
    const uint32_t* __restrict__ vp, short* __restrict__ yq) {
  __shared__ uint32_t kT[32][8], vT[32][8];
  __shared__ int Zs[32][32];
  const int bh = blockIdx.x, chunk = blockIdx.y;
  const int b = bh / H_, h = bh % H_;
  const int tid = threadIdx.x, lane = tid & 63, w = tid >> 6;
  const int d = tid & 31, nn = tid >> 5;
  const short one32 = f2bf_bits(32.f);
  const short zer = 0;
  float vst[7];
#pragma unroll
  for (int i = 0; i < 7; ++i) vst[i] = 0.f;
  for (int t = 0; t < T_; ++t) {
    int tbh = (t * B_ + b) * H_ + h;
    size_t base = (size_t)tbh * NT_;
    uint32_t km = (tid < NT_) ? kp[base + tid] : 0u;
    uint32_t vm = (tid < NT_) ? vp[base + tid] : 0u;
#pragma unroll
    for (int j = 0; j < 32; ++j) {
      unsigned long long bk = __ballot((km >> j) & 1u);
      unsigned long long bv = __ballot((vm >> j) & 1u);
      if (lane == 0) {
        kT[j][2 * w] = (uint32_t)bk; kT[j][2 * w + 1] = (uint32_t)(bk >> 32);
        vT[j][2 * w] = (uint32_t)bv; vT[j][2 * w + 1] = (uint32_t)(bv >> 32);
      }
    }
    __syncthreads();
    for (int pz = tid; pz < 1024; pz += 256) {
      int j = pz >> 5, dd = pz & 31;
      int zz = 0;
#pragma unroll
      for (int ww = 0; ww < 8; ++ww) zz += __popc(kT[j][ww] & vT[dd][ww]);
      Zs[j][dd] = zz;
    }
    __syncthreads();
    int zc[32];
#pragma unroll
    for (int j = 0; j < 32; ++j) zc[j] = Zs[j][d];
#pragma unroll
    for (int i = 0; i < 7; ++i) {
      int no = i * 8 + nn;
      if (no < 49) {
        int n = chunk * 49 + no;
        uint32_t qm = qp[base + n];
        int a = 0;
#pragma unroll
        for (int j = 0; j < 32; ++j) a += ((qm >> j) & 1u) ? zc[j] : 0;
        float y = 0.125f * (float)a;          // exact multiple of 1/8
        float v = vst[i];
        v = v + (y - v) * 0.5f;
        short outv;
        if (v - 0.5f >= 0.f) { v = 0.f; outv = one32; } else { outv = zer; }
        vst[i] = v;
        yq[((size_t)(t * B_ + b) * NT_ + n) * C_ + h * 32 + d] = outv;
      }
    }
    __syncthreads();
  }
}

// final BN + LIF -> d_out (f32 spikes); reads i16 q
__global__ __launch_bounds__(384) void bn_lif_out_kernel(
    const short* __restrict__ p2, const float* __restrict__ bn,
    const unsigned* __restrict__ slots,
    const float* __restrict__ g, const float* __restrict__ beta,
    float* __restrict__ out) {
  int c = threadIdx.x, n = blockIdx.x, b = blockIdx.y;
  float invSN1 = 1.0f / sn_from_slot(slots, 4);
  float mean = bn[c * 2 + 0], sd = bn[c * 2 + 1];
  float gg = g[c], bb = beta[c];
  float v = 0.f;
  for (int t = 0; t < T_; ++t) {
    size_t idx = ((size_t)(t * B_ + b) * NT_ + n) * C_ + c;
    float p = (float)p2[idx] * invSN1;
    float o = (gg * (p - mean)) / sd + bb;
    out[idx] = lif_step(v, o, 1.0f);
  }
}

// ---------------- launcher (9 kernels + 1 tiny memset) ----------------
extern "C" void kernel_launch(void* const* d_in, const int* in_sizes, int n_in,
                              void* d_out, int out_size, void* d_ws, size_t ws_size,
                              hipStream_t stream) {
  (void)in_sizes; (void)n_in; (void)out_size; (void)ws_size;
  const float* x = (const float*)d_in[0];
  const float* W[4]  = {(const float*)d_in[1],  (const float*)d_in[5],
                        (const float*)d_in[9],  (const float*)d_in[13]};
  const float* bv[4] = {(const float*)d_in[2],  (const float*)d_in[6],
                        (const float*)d_in[10], (const float*)d_in[14]};
  const float* g[4]  = {(const float*)d_in[3],  (const float*)d_in[7],
                        (const float*)d_in[11], (const float*)d_in[15]};
  const float* be[4] = {(const float*)d_in[4],  (const float*)d_in[8],
                        (const float*)d_in[12], (const float*)d_in[16]};
  float* out = (float*)d_out;

  char* ws = (char*)d_ws;
  unsigned*  slots = (unsigned*)(ws + 0x0000);    // [16] u32
  float*     bn1   = (float*)(ws + 0x0080);       // [1152][2] f32
  float*     bn2   = (float*)(ws + 0x2480);       // [384][2] f32
  float*     ccq   = (float*)(ws + 0x3400);       // [4][384] f32
  long long* part1 = (long long*)(ws + 0x10000);  // [98][1152][2] i64 (1.77MB)
  long long* part2 = (long long*)(ws + 0x1D0000); // [98][384][2] i64
  uint32_t*  pack  = (uint32_t*)(ws + 0x270000);  // [3][150528] u32
  short*     wq    = (short*)(ws + 0x460000);     // [4][384][384] bf16
  short*     xq    = (short*)(ws + 0x600000);     // [12544][384] bf16
  short*     yq    = (short*)(ws + 0xF80000);     // [12544][384] bf16 (32*spike)
  short*     pwide = (short*)(ws + 0x1900000);    // [12544][1152] i16 q (28.9MB)
  short*     p2    = (short*)(ws + 0x3500000);    // [12544][384] i16 q

  hipMemsetAsync(slots, 0, 64, stream);

  absmax_all_kernel<<<dim3(128, 5), 256, 0, stream>>>(
      x, W[0], W[1], W[2], W[3], bv[0], bv[1], bv[2], bv[3], slots);
  quant_all_kernel<<<dim3(1176, 5), 256, 0, stream>>>(
      x, W[0], W[1], W[2], W[3], bv[0], bv[1], bv[2], bv[3], slots, xq, wq, ccq);

  // stage 1: wide GEMM (N=1152 = q|k|v) -> i16 q + partial stats; BN finalize; BN+LIF+pack
  mfma_gemm_kernel<<<dim3(98, 9), 256, 0, stream>>>(
      xq, wq, ccq, slots, 0, NW_, pwide, part1);
  stats_final_kernel<<<3, 384, 0, stream>>>(part1, slots, 1, NW_, bn1);
  bn_lif_pack_kernel<<<dim3(NT_, B_, 3), 384, 0, stream>>>(
      pwide, bn1, slots, g[0], g[1], g[2], be[0], be[1], be[2], pack);

  // attention + attn_lif fused (Z = k^T v per (t,b,h), q·Z·0.125, vth=0.5)
  attn_fused_kernel<<<dim3(B_ * H_, 4), 256, 0, stream>>>(
      pack, pack + 150528, pack + 2 * 150528, yq);

  // stage 2: proj GEMM -> i16 q + partials; BN finalize; BN+LIF -> out
  mfma_gemm_kernel<<<dim3(98, 3), 256, 0, stream>>>(
      yq, wq + 3ull * C_ * C_, ccq + 3 * C_, slots, -1, C_, p2, part2);
  stats_final_kernel<<<1, 384, 0, stream>>>(part2, slots, 4, C_, bn2);
  bn_lif_out_kernel<<<dim3(NT_, B_), 384, 0, stream>>>(p2, bn2, slots, g[3], be[3], out);
}